// Round 7
// baseline (557.290 us; speedup 1.0000x reference)
//
#include <hip/hip_runtime.h>
#include <hip/hip_bf16.h>

typedef __attribute__((ext_vector_type(8))) short bf16x8;
typedef __attribute__((ext_vector_type(4))) float f32x4;
typedef __attribute__((ext_vector_type(16))) float f32x16;

#define DEVI __device__ __forceinline__

DEVI unsigned short f2bf(float f) {
  union { float f; unsigned u; } v; v.f = f;
  unsigned r = v.u + 0x7FFFu + ((v.u >> 16) & 1u);
  return (unsigned short)(r >> 16);
}

DEVI unsigned cvtpk(float lo, float hi) {
  unsigned r;
  asm("v_cvt_pk_bf16_f32 %0, %1, %2" : "=v"(r) : "v"(lo), "v"(hi));
  return r;
}

DEVI void gload16(const void* g, void* l) {
  __builtin_amdgcn_global_load_lds(
      (const __attribute__((address_space(1))) unsigned int*)g,
      (__attribute__((address_space(3))) unsigned int*)l, 16, 0, 0);
}

// ---------------- fp32 -> bf16 convert ----------------
__global__ void k_cvt(const float* __restrict__ in, unsigned short* __restrict__ out, int n4) {
  int i = blockIdx.x * blockDim.x + threadIdx.x;
  int stride = gridDim.x * blockDim.x;
  for (; i < n4; i += stride) {
    float4 v = ((const float4*)in)[i];
    ushort4 o;
    o.x = f2bf(v.x); o.y = f2bf(v.y); o.z = f2bf(v.z); o.w = f2bf(v.w);
    ((ushort4*)out)[i] = o;
  }
}

// ------------- transpose [R][C] f32 -> [C][R] bf16, batched over blockIdx.z -------------
__global__ void k_tr(const float* __restrict__ in, unsigned short* __restrict__ out, int R, int C) {
  __shared__ float t[32][33];
  size_t base = (size_t)blockIdx.z * R * C;
  int r0 = blockIdx.y * 32, c0 = blockIdx.x * 32;
  int tx = threadIdx.x, ty = threadIdx.y;
  for (int i = 0; i < 32; i += 8)
    t[ty + i][tx] = in[base + (size_t)(r0 + ty + i) * C + (c0 + tx)];
  __syncthreads();
  for (int i = 0; i < 32; i += 8)
    out[base + (size_t)(c0 + ty + i) * R + (r0 + tx)] = f2bf(t[tx][ty + i]);
}

// ---------------- fused QKV GEMM: [16384,1024] x [3072,1024]^T ----------------
__global__ __launch_bounds__(512, 4) void k_gemmqkv(
    const unsigned short* __restrict__ A,
    const unsigned short* __restrict__ B,
    const float* __restrict__ bq, const float* __restrict__ bk,
    const float* __restrict__ bv,
    unsigned short* __restrict__ Qb, unsigned short* __restrict__ Kg,
    unsigned short* __restrict__ Vt, float qscale)
{
  __shared__ unsigned short As[128 * 64];
  __shared__ unsigned short Bs[256 * 64];
  int tid = threadIdx.x;
  int w = tid >> 6, l = tid & 63;
  int lg = l >> 4, lm = l & 15;
  int wr = w >> 2, wc = w & 3;
  int row0 = blockIdx.y * 128, col0 = blockIdx.x * 256;

  const f32x4 fz = {0.f, 0.f, 0.f, 0.f};
  f32x4 acc[4][4];
  for (int i = 0; i < 4; i++) for (int j = 0; j < 4; j++) acc[i][j] = fz;

  for (int t = 0; t < 16; ++t) {
    int k0 = t << 6;
    __syncthreads();
#pragma unroll
    for (int j = 0; j < 2; ++j) {
      int ch = j * 512 + tid;
      int row = ch >> 3, cirp = (ch & 7) ^ (row & 7);
      gload16(A + (size_t)(row0 + row) * 1024 + k0 + cirp * 8,
              As + (size_t)(j * 512 + w * 64) * 8);
    }
#pragma unroll
    for (int j = 0; j < 4; ++j) {
      int ch = j * 512 + tid;
      int row = ch >> 3, cirp = (ch & 7) ^ (row & 7);
      gload16(B + (size_t)(col0 + row) * 1024 + k0 + cirp * 8,
              Bs + (size_t)(j * 512 + w * 64) * 8);
    }
    __syncthreads();
#pragma unroll
    for (int kt = 0; kt < 2; ++kt) {
      bf16x8 bfr[4];
#pragma unroll
      for (int ni = 0; ni < 4; ++ni) {
        int r = wc * 64 + ni * 16 + lm;
        bfr[ni] = *(const bf16x8*)((const char*)Bs + r * 128 + ((kt * 64 + lg * 16) ^ ((r & 7) << 4)));
      }
#pragma unroll
      for (int mi = 0; mi < 4; ++mi) {
        int r = wr * 64 + mi * 16 + lm;
        bf16x8 afr = *(const bf16x8*)((const char*)As + r * 128 + ((kt * 64 + lg * 16) ^ ((r & 7) << 4)));
#pragma unroll
        for (int ni = 0; ni < 4; ++ni)
          acc[mi][ni] = __builtin_amdgcn_mfma_f32_16x16x32_bf16(afr, bfr[ni], acc[mi][ni], 0, 0, 0);
      }
    }
  }

  int sel = col0 >> 10;                 // block-uniform: 0=Q, 1=K, 2=V
  const float* bb = sel == 0 ? bq : (sel == 1 ? bk : bv);
#pragma unroll
  for (int mi = 0; mi < 4; ++mi) {
#pragma unroll
    for (int ni = 0; ni < 4; ++ni) {
#pragma unroll
      for (int q = 0; q < 4; ++q) {
        int rg = row0 + wr * 64 + mi * 16 + lg * 4 + q;
        int cg = col0 + wc * 64 + ni * 16 + lm;
        int cl = cg & 1023;
        float val = acc[mi][ni][q] + bb[cl];
        int bI = rg >> 11, s = rg & 2047;
        int nn = cl >> 8, d = cl & 255;
        if (sel == 0) {
          Qb[(size_t)rg * 1024 + cl] = f2bf(val * qscale);
        } else if (sel == 1) {
          Kg[((size_t)((nn * 8 + bI) * 32 + (d >> 3))) * 16384 + (size_t)s * 8 + (d & 7)] = f2bf(val);
        } else {
          int t2 = s >> 6, u = s & 63;
          int p = ((u >> 4) & 3) * 2 + ((u >> 2) & 1);
          int jv = ((u >> 3) & 1) * 4 + (u & 3);
          Vt[(((size_t)(nn * 8 + bI) * 32 + t2) * 2048 + p * 256 + d) * 8 + jv] = f2bf(val);
        }
      }
    }
  }
}

// ---------------- output GEMM: [16384,1024] x [256,1024]^T -> fp32 + bo ----------------
__global__ __launch_bounds__(512, 4) void k_gemmo(
    const unsigned short* __restrict__ A,
    const unsigned short* __restrict__ B,
    const float* __restrict__ bias,
    float* __restrict__ Cout)
{
  __shared__ unsigned short As[128 * 64];
  __shared__ unsigned short Bs[256 * 64];
  int tid = threadIdx.x;
  int w = tid >> 6, l = tid & 63;
  int lg = l >> 4, lm = l & 15;
  int wr = w >> 2, wc = w & 3;
  int row0 = blockIdx.y * 128;

  const f32x4 fz = {0.f, 0.f, 0.f, 0.f};
  f32x4 acc[4][4];
  for (int i = 0; i < 4; i++) for (int j = 0; j < 4; j++) acc[i][j] = fz;

  for (int t = 0; t < 16; ++t) {
    int k0 = t << 6;
    __syncthreads();
#pragma unroll
    for (int j = 0; j < 2; ++j) {
      int ch = j * 512 + tid;
      int row = ch >> 3, cirp = (ch & 7) ^ (row & 7);
      gload16(A + (size_t)(row0 + row) * 1024 + k0 + cirp * 8,
              As + (size_t)(j * 512 + w * 64) * 8);
    }
#pragma unroll
    for (int j = 0; j < 4; ++j) {
      int ch = j * 512 + tid;
      int row = ch >> 3, cirp = (ch & 7) ^ (row & 7);
      gload16(B + (size_t)(row) * 1024 + k0 + cirp * 8,
              Bs + (size_t)(j * 512 + w * 64) * 8);
    }
    __syncthreads();
#pragma unroll
    for (int kt = 0; kt < 2; ++kt) {
      bf16x8 bfr[4];
#pragma unroll
      for (int ni = 0; ni < 4; ++ni) {
        int r = wc * 64 + ni * 16 + lm;
        bfr[ni] = *(const bf16x8*)((const char*)Bs + r * 128 + ((kt * 64 + lg * 16) ^ ((r & 7) << 4)));
      }
#pragma unroll
      for (int mi = 0; mi < 4; ++mi) {
        int r = wr * 64 + mi * 16 + lm;
        bf16x8 afr = *(const bf16x8*)((const char*)As + r * 128 + ((kt * 64 + lg * 16) ^ ((r & 7) << 4)));
#pragma unroll
        for (int ni = 0; ni < 4; ++ni)
          acc[mi][ni] = __builtin_amdgcn_mfma_f32_16x16x32_bf16(afr, bfr[ni], acc[mi][ni], 0, 0, 0);
      }
    }
  }

#pragma unroll
  for (int mi = 0; mi < 4; ++mi)
#pragma unroll
    for (int ni = 0; ni < 4; ++ni)
#pragma unroll
      for (int q = 0; q < 4; ++q) {
        int rg = row0 + wr * 64 + mi * 16 + lg * 4 + q;
        int cg = wc * 64 + ni * 16 + lm;
        Cout[(size_t)rg * 256 + cg] = acc[mi][ni][q] + bias[cg];
      }
}

// ---------------- flash attention (pipelined, 16 waves / 256 q rows) ----------------
// block = 256 q rows of one (n,b); 16 waves: qg=w&7 (32 q rows), dh=w>>3 (d half).
// iter t: [K-prefetch(t+1)] [QK(t)] [PV(t-1)] [sync] [V-prefetch(t+1)] [softmax(t)->pa(t)] [sync]
__global__ __launch_bounds__(1024, 4) void k_attn(
    const unsigned short* __restrict__ Qb,
    const unsigned short* __restrict__ Kg,
    const unsigned short* __restrict__ Vt,
    unsigned short* __restrict__ comb)
{
  __shared__ unsigned short Ks[2][2048 * 8];
  __shared__ unsigned short Vs[2][2048 * 8];

  int i = blockIdx.x;
  int c = i & 7, j = i >> 3;
  int nbb = c + 8 * (j >> 3);
  int qt = j & 7;
  int n = nbb >> 3, b = nbb & 7;
  int q0 = qt * 256;

  int tid = threadIdx.x;
  int w = tid >> 6, l = tid & 63;
  int m = l & 31, g = l >> 5;
  int qg = w & 7, dh = w >> 3;

  bf16x8 qf[16];
  {
    const unsigned short* qbase = Qb + (size_t)(b * 2048 + q0 + qg * 32 + m) * 1024 + n * 256 + g * 8;
#pragma unroll
    for (int ks = 0; ks < 16; ++ks)
      qf[ks] = *(const bf16x8*)(qbase + ks * 16);
  }

  f32x16 ao[4];
#pragma unroll
  for (int dt = 0; dt < 4; ++dt)
#pragma unroll
    for (int r = 0; r < 16; ++r) ao[dt][r] = 0.f;
  float m_s = -1e30f, l_s = 0.f;
  bf16x8 pa[4];

  // staging: wave stages K planes w*2..w*2+1 and V granule rows w*128..+128
  const unsigned short* kpl = Kg + (((size_t)(n * 8 + b) * 32 + w * 2) * 16384) + (size_t)l * 8;
  const unsigned short* vpl = Vt + ((size_t)(n * 8 + b) * 65536 + w * 128 + l) * 8;

#pragma unroll
  for (int jj = 0; jj < 2; ++jj) {
    gload16(kpl + jj * 16384, Ks[0] + ((w * 2 + jj) * 64) * 8);
    gload16(vpl + jj * 512,   Vs[0] + (w * 128 + jj * 64) * 8);
  }
  __syncthreads();

  for (int t = 0; t < 32; ++t) {
    int cur = t & 1;
    const unsigned short* Kc = Ks[cur];

    // K-prefetch(t+1): targets Ks[cur^1], last read at iter t-1 (safe).
    if (t < 31) {
      int tn = t + 1;
#pragma unroll
      for (int jj = 0; jj < 2; ++jj)
        gload16(kpl + jj * 16384 + tn * 512, Ks[cur ^ 1] + ((w * 2 + jj) * 64) * 8);
    }

    // QK^T swapped: s0/s1 = S[kv 0..31 / 32..63][q=lane&31]
    f32x16 s0, s1;
#pragma unroll
    for (int r = 0; r < 16; ++r) { s0[r] = 0.f; s1[r] = 0.f; }
    __builtin_amdgcn_s_setprio(1);
#pragma unroll
    for (int ks = 0; ks < 16; ++ks) {
      bf16x8 k0 = *(const bf16x8*)(Kc + ((2 * ks + g) * 64 + m) * 8);
      bf16x8 k1 = *(const bf16x8*)(Kc + ((2 * ks + g) * 64 + 32 + m) * 8);
      s0 = __builtin_amdgcn_mfma_f32_32x32x16_bf16(k0, qf[ks], s0, 0, 0, 0);
      s1 = __builtin_amdgcn_mfma_f32_32x32x16_bf16(k1, qf[ks], s1, 0, 0, 0);
    }

    // PV(t-1): reads Vs[cur^1] (V(t-1)); pa packed with m_(t-1); ao currently m_(t-1)-scaled.
    if (t > 0) {
      const unsigned short* Vp = Vs[cur ^ 1];
#pragma unroll
      for (int dt = 0; dt < 4; ++dt) {
        int vrow = dh * 128 + dt * 32 + m;
#pragma unroll
        for (int ks2 = 0; ks2 < 4; ++ks2) {
          bf16x8 vf = *(const bf16x8*)(Vp + ((2 * ks2 + g) * 256 + vrow) * 8);
          ao[dt] = __builtin_amdgcn_mfma_f32_32x32x16_bf16(pa[ks2], vf, ao[dt], 0, 0, 0);
        }
      }
    }
    __builtin_amdgcn_s_setprio(0);

    // mid barrier: all waves done reading Vs[cur^1]; drains K-prefetch (cheap).
    __syncthreads();

    // V-prefetch(t+1) into Vs[cur^1]
    if (t < 31) {
      int tn = t + 1;
#pragma unroll
      for (int jj = 0; jj < 2; ++jj)
        gload16(vpl + (size_t)tn * 16384 + jj * 512, Vs[cur ^ 1] + (w * 128 + jj * 64) * 8);
    }

    // ---- softmax(t) (exp2 domain; Q pre-scaled) ----
    float tm[16];
#pragma unroll
    for (int r = 0; r < 16; ++r) tm[r] = fmaxf(s0[r], s1[r]);
#pragma unroll
    for (int d = 8; d > 0; d >>= 1)
#pragma unroll
      for (int r = 0; r < d; ++r) tm[r] = fmaxf(tm[r], tm[r + d]);
    float vm = fmaxf(tm[0], __shfl_xor(tm[0], 32));

    if (__any(vm > m_s + 8.f)) {
      float mn = fmaxf(m_s, vm);
      float f = exp2f(m_s - mn);
      m_s = mn; l_s *= f;
#pragma unroll
      for (int r = 0; r < 16; ++r) {
        float fr = __shfl(f, 4 * g + (r & 3) + 8 * (r >> 2));
        ao[0][r] *= fr; ao[1][r] *= fr; ao[2][r] *= fr; ao[3][r] *= fr;
      }
    }

    float p0[16], p1[16];
#pragma unroll
    for (int r = 0; r < 16; ++r) {
      p0[r] = exp2f(s0[r] - m_s);
      p1[r] = exp2f(s1[r] - m_s);
    }
    float ts[16];
#pragma unroll
    for (int r = 0; r < 16; ++r) ts[r] = p0[r] + p1[r];
#pragma unroll
    for (int d = 8; d > 0; d >>= 1)
#pragma unroll
      for (int r = 0; r < d; ++r) ts[r] += ts[r + d];
    l_s += ts[0] + __shfl_xor(ts[0], 32);

    // pack P via v_cvt_pk_bf16_f32: pa[0]=p0[0..7], pa[1]=p0[8..15], pa[2]=p1[0..7], pa[3]=p1[8..15]
    {
      union { unsigned u[4]; bf16x8 v; } w0, w1, w2, w3;
#pragma unroll
      for (int wd = 0; wd < 4; ++wd) {
        w0.u[wd] = cvtpk(p0[2 * wd], p0[2 * wd + 1]);
        w1.u[wd] = cvtpk(p0[8 + 2 * wd], p0[8 + 2 * wd + 1]);
        w2.u[wd] = cvtpk(p1[2 * wd], p1[2 * wd + 1]);
        w3.u[wd] = cvtpk(p1[8 + 2 * wd], p1[8 + 2 * wd + 1]);
      }
      pa[0] = w0.v; pa[1] = w1.v; pa[2] = w2.v; pa[3] = w3.v;
    }

    // end barrier: drains V-prefetch; next iter reads Ks/Vs[cur^1].
    __syncthreads();
  }

  // final PV(31): V(31) lives in Vs[1]
  {
    const unsigned short* Vp = Vs[1];
    __builtin_amdgcn_s_setprio(1);
#pragma unroll
    for (int dt = 0; dt < 4; ++dt) {
      int vrow = dh * 128 + dt * 32 + m;
#pragma unroll
      for (int ks2 = 0; ks2 < 4; ++ks2) {
        bf16x8 vf = *(const bf16x8*)(Vp + ((2 * ks2 + g) * 256 + vrow) * 8);
        ao[dt] = __builtin_amdgcn_mfma_f32_32x32x16_bf16(pa[ks2], vf, ao[dt], 0, 0, 0);
      }
    }
    __builtin_amdgcn_s_setprio(0);
  }

  // epilogue
  float rinv[16];
#pragma unroll
  for (int r = 0; r < 16; ++r) {
    float lr = __shfl(l_s, 4 * g + (r & 3) + 8 * (r >> 2));
    rinv[r] = 1.f / lr;
  }
#pragma unroll
  for (int dt = 0; dt < 4; ++dt) {
    int col = n * 256 + dh * 128 + dt * 32 + m;
#pragma unroll
    for (int r = 0; r < 16; ++r) {
      int rowq = q0 + qg * 32 + 4 * g + (r & 3) + 8 * (r >> 2);
      comb[(size_t)(b * 2048 + rowq) * 1024 + col] = f2bf(ao[dt][r] * rinv[r]);
    }
  }
}

extern "C" void kernel_launch(void* const* d_in, const int* in_sizes, int n_in,
                              void* d_out, int out_size, void* d_ws, size_t ws_size,
                              hipStream_t stream) {
  const float* x  = (const float*)d_in[0];
  const float* Wq = (const float*)d_in[1];
  const float* bq = (const float*)d_in[2];
  const float* Wk = (const float*)d_in[3];
  const float* bk = (const float*)d_in[4];
  const float* Wv = (const float*)d_in[5];
  const float* bv = (const float*)d_in[6];
  const float* Wo = (const float*)d_in[7];
  const float* bo = (const float*)d_in[8];

  const size_t MB = 1ull << 20;
  char* ws = (char*)d_ws;
  unsigned short* xb  = (unsigned short*)(ws);            // 32MB (reused as comb)
  unsigned short* Wqt = (unsigned short*)(ws + 32 * MB);  // 2MB, contiguous B [3072][1024] starts here
  unsigned short* Wkt = (unsigned short*)(ws + 34 * MB);  // 2MB
  unsigned short* Wvt = (unsigned short*)(ws + 36 * MB);  // 2MB
  unsigned short* Wot = (unsigned short*)(ws + 38 * MB);  // 0.5MB
  unsigned short* Qb  = (unsigned short*)(ws + 40 * MB);  // 32MB
  unsigned short* Kg  = (unsigned short*)(ws + 72 * MB);  // 32MB (fragment-plane layout)
  unsigned short* Vt  = (unsigned short*)(ws + 104 * MB); // 32MB (granule layout, end: 136MB)
  unsigned short* comb = xb;

  k_cvt<<<2048, 256, 0, stream>>>(x, xb, 16384 * 1024 / 4);
  dim3 trb(32, 8);
  k_tr<<<dim3(8, 32, 4), trb, 0, stream>>>(Wq, Wqt, 1024, 256);
  k_tr<<<dim3(8, 32, 4), trb, 0, stream>>>(Wk, Wkt, 1024, 256);
  k_tr<<<dim3(8, 32, 4), trb, 0, stream>>>(Wv, Wvt, 1024, 256);
  k_tr<<<dim3(8, 32, 1), trb, 0, stream>>>(Wo, Wot, 1024, 256);

  const float qscale = 0.0625f * 1.44269504088896f;  // 1/sqrt(256) * log2(e)
  k_gemmqkv<<<dim3(12, 128), 512, 0, stream>>>(xb, Wqt, bq, bk, bv, Qb, Kg, Vt, qscale);

  k_attn<<<256, 1024, 0, stream>>>(Qb, Kg, Vt, comb);

  k_gemmo<<<dim3(1, 128), 512, 0, stream>>>(comb, Wot, bo, (float*)d_out);
}

// Round 8
// 557.189 us; speedup vs baseline: 1.0002x; 1.0002x over previous
//
#include <hip/hip_runtime.h>
#include <hip/hip_bf16.h>

typedef __attribute__((ext_vector_type(8))) short bf16x8;
typedef __attribute__((ext_vector_type(4))) float f32x4;
typedef __attribute__((ext_vector_type(16))) float f32x16;

#define DEVI __device__ __forceinline__

DEVI unsigned short f2bf(float f) {
  union { float f; unsigned u; } v; v.f = f;
  unsigned r = v.u + 0x7FFFu + ((v.u >> 16) & 1u);
  return (unsigned short)(r >> 16);
}

DEVI unsigned cvtpk(float lo, float hi) {
  unsigned r;
  asm("v_cvt_pk_bf16_f32 %0, %1, %2" : "=v"(r) : "v"(lo), "v"(hi));
  return r;
}

DEVI void gload16(const void* g, void* l) {
  __builtin_amdgcn_global_load_lds(
      (const __attribute__((address_space(1))) unsigned int*)g,
      (__attribute__((address_space(3))) unsigned int*)l, 16, 0, 0);
}

// ---------------- fp32 -> bf16 convert ----------------
__global__ void k_cvt(const float* __restrict__ in, unsigned short* __restrict__ out, int n4) {
  int i = blockIdx.x * blockDim.x + threadIdx.x;
  int stride = gridDim.x * blockDim.x;
  for (; i < n4; i += stride) {
    float4 v = ((const float4*)in)[i];
    ushort4 o;
    o.x = f2bf(v.x); o.y = f2bf(v.y); o.z = f2bf(v.z); o.w = f2bf(v.w);
    ((ushort4*)out)[i] = o;
  }
}

// ------------- transpose [R][C] f32 -> [C][R] bf16, batched over blockIdx.z -------------
__global__ void k_tr(const float* __restrict__ in, unsigned short* __restrict__ out, int R, int C) {
  __shared__ float t[32][33];
  size_t base = (size_t)blockIdx.z * R * C;
  int r0 = blockIdx.y * 32, c0 = blockIdx.x * 32;
  int tx = threadIdx.x, ty = threadIdx.y;
  for (int i = 0; i < 32; i += 8)
    t[ty + i][tx] = in[base + (size_t)(r0 + ty + i) * C + (c0 + tx)];
  __syncthreads();
  for (int i = 0; i < 32; i += 8)
    out[base + (size_t)(c0 + ty + i) * R + (r0 + tx)] = f2bf(t[tx][ty + i]);
}

// ---------------- fused QKV GEMM: [16384,1024] x [3072,1024]^T ----------------
__global__ __launch_bounds__(512, 4) void k_gemmqkv(
    const unsigned short* __restrict__ A,
    const unsigned short* __restrict__ B,
    const float* __restrict__ bq, const float* __restrict__ bk,
    const float* __restrict__ bv,
    unsigned short* __restrict__ Qb, unsigned short* __restrict__ Kg,
    unsigned short* __restrict__ Vt, float qscale)
{
  __shared__ unsigned short As[128 * 64];
  __shared__ unsigned short Bs[256 * 64];
  int tid = threadIdx.x;
  int w = tid >> 6, l = tid & 63;
  int lg = l >> 4, lm = l & 15;
  int wr = w >> 2, wc = w & 3;
  int row0 = blockIdx.y * 128, col0 = blockIdx.x * 256;

  const f32x4 fz = {0.f, 0.f, 0.f, 0.f};
  f32x4 acc[4][4];
  for (int i = 0; i < 4; i++) for (int j = 0; j < 4; j++) acc[i][j] = fz;

  for (int t = 0; t < 16; ++t) {
    int k0 = t << 6;
    __syncthreads();
#pragma unroll
    for (int j = 0; j < 2; ++j) {
      int ch = j * 512 + tid;
      int row = ch >> 3, cirp = (ch & 7) ^ (row & 7);
      gload16(A + (size_t)(row0 + row) * 1024 + k0 + cirp * 8,
              As + (size_t)(j * 512 + w * 64) * 8);
    }
#pragma unroll
    for (int j = 0; j < 4; ++j) {
      int ch = j * 512 + tid;
      int row = ch >> 3, cirp = (ch & 7) ^ (row & 7);
      gload16(B + (size_t)(col0 + row) * 1024 + k0 + cirp * 8,
              Bs + (size_t)(j * 512 + w * 64) * 8);
    }
    __syncthreads();
#pragma unroll
    for (int kt = 0; kt < 2; ++kt) {
      bf16x8 bfr[4];
#pragma unroll
      for (int ni = 0; ni < 4; ++ni) {
        int r = wc * 64 + ni * 16 + lm;
        bfr[ni] = *(const bf16x8*)((const char*)Bs + r * 128 + ((kt * 64 + lg * 16) ^ ((r & 7) << 4)));
      }
#pragma unroll
      for (int mi = 0; mi < 4; ++mi) {
        int r = wr * 64 + mi * 16 + lm;
        bf16x8 afr = *(const bf16x8*)((const char*)As + r * 128 + ((kt * 64 + lg * 16) ^ ((r & 7) << 4)));
#pragma unroll
        for (int ni = 0; ni < 4; ++ni)
          acc[mi][ni] = __builtin_amdgcn_mfma_f32_16x16x32_bf16(afr, bfr[ni], acc[mi][ni], 0, 0, 0);
      }
    }
  }

  int sel = col0 >> 10;                 // block-uniform: 0=Q, 1=K, 2=V
  const float* bb = sel == 0 ? bq : (sel == 1 ? bk : bv);
#pragma unroll
  for (int mi = 0; mi < 4; ++mi) {
#pragma unroll
    for (int ni = 0; ni < 4; ++ni) {
#pragma unroll
      for (int q = 0; q < 4; ++q) {
        int rg = row0 + wr * 64 + mi * 16 + lg * 4 + q;
        int cg = col0 + wc * 64 + ni * 16 + lm;
        int cl = cg & 1023;
        float val = acc[mi][ni][q] + bb[cl];
        int bI = rg >> 11, s = rg & 2047;
        int nn = cl >> 8, d = cl & 255;
        if (sel == 0) {
          Qb[(size_t)rg * 1024 + cl] = f2bf(val * qscale);
        } else if (sel == 1) {
          Kg[((size_t)((nn * 8 + bI) * 32 + (d >> 3))) * 16384 + (size_t)s * 8 + (d & 7)] = f2bf(val);
        } else {
          int t2 = s >> 6, u = s & 63;
          int p = ((u >> 4) & 3) * 2 + ((u >> 2) & 1);
          int jv = ((u >> 3) & 1) * 4 + (u & 3);
          Vt[(((size_t)(nn * 8 + bI) * 32 + t2) * 2048 + p * 256 + d) * 8 + jv] = f2bf(val);
        }
      }
    }
  }
}

// ---------------- output GEMM: [16384,1024] x [256,1024]^T -> fp32 + bo ----------------
__global__ __launch_bounds__(512, 4) void k_gemmo(
    const unsigned short* __restrict__ A,
    const unsigned short* __restrict__ B,
    const float* __restrict__ bias,
    float* __restrict__ Cout)
{
  __shared__ unsigned short As[128 * 64];
  __shared__ unsigned short Bs[256 * 64];
  int tid = threadIdx.x;
  int w = tid >> 6, l = tid & 63;
  int lg = l >> 4, lm = l & 15;
  int wr = w >> 2, wc = w & 3;
  int row0 = blockIdx.y * 128;

  const f32x4 fz = {0.f, 0.f, 0.f, 0.f};
  f32x4 acc[4][4];
  for (int i = 0; i < 4; i++) for (int j = 0; j < 4; j++) acc[i][j] = fz;

  for (int t = 0; t < 16; ++t) {
    int k0 = t << 6;
    __syncthreads();
#pragma unroll
    for (int j = 0; j < 2; ++j) {
      int ch = j * 512 + tid;
      int row = ch >> 3, cirp = (ch & 7) ^ (row & 7);
      gload16(A + (size_t)(row0 + row) * 1024 + k0 + cirp * 8,
              As + (size_t)(j * 512 + w * 64) * 8);
    }
#pragma unroll
    for (int j = 0; j < 4; ++j) {
      int ch = j * 512 + tid;
      int row = ch >> 3, cirp = (ch & 7) ^ (row & 7);
      gload16(B + (size_t)(row) * 1024 + k0 + cirp * 8,
              Bs + (size_t)(j * 512 + w * 64) * 8);
    }
    __syncthreads();
#pragma unroll
    for (int kt = 0; kt < 2; ++kt) {
      bf16x8 bfr[4];
#pragma unroll
      for (int ni = 0; ni < 4; ++ni) {
        int r = wc * 64 + ni * 16 + lm;
        bfr[ni] = *(const bf16x8*)((const char*)Bs + r * 128 + ((kt * 64 + lg * 16) ^ ((r & 7) << 4)));
      }
#pragma unroll
      for (int mi = 0; mi < 4; ++mi) {
        int r = wr * 64 + mi * 16 + lm;
        bf16x8 afr = *(const bf16x8*)((const char*)As + r * 128 + ((kt * 64 + lg * 16) ^ ((r & 7) << 4)));
#pragma unroll
        for (int ni = 0; ni < 4; ++ni)
          acc[mi][ni] = __builtin_amdgcn_mfma_f32_16x16x32_bf16(afr, bfr[ni], acc[mi][ni], 0, 0, 0);
      }
    }
  }

#pragma unroll
  for (int mi = 0; mi < 4; ++mi)
#pragma unroll
    for (int ni = 0; ni < 4; ++ni)
#pragma unroll
      for (int q = 0; q < 4; ++q) {
        int rg = row0 + wr * 64 + mi * 16 + lg * 4 + q;
        int cg = wc * 64 + ni * 16 + lm;
        Cout[(size_t)rg * 256 + cg] = acc[mi][ni][q] + bias[cg];
      }
}

// ---------------- flash attention (pipelined, 16 waves / 256 q rows) ----------------
// block = 256 q rows of one (n,b); 16 waves: qg=w&7 (32 q rows), dh=w>>3 (d half).
// iter t: [K-prefetch(t+1)] [QK(t)] [PV(t-1)] [sync] [V-prefetch(t+1)] [softmax(t)->pa(t)] [sync]
__global__ __launch_bounds__(1024, 2) void k_attn(
    const unsigned short* __restrict__ Qb,
    const unsigned short* __restrict__ Kg,
    const unsigned short* __restrict__ Vt,
    unsigned short* __restrict__ comb)
{
  __shared__ unsigned short Ks[2][2048 * 8];
  __shared__ unsigned short Vs[2][2048 * 8];

  int i = blockIdx.x;
  int c = i & 7, j = i >> 3;
  int nbb = c + 8 * (j >> 3);
  int qt = j & 7;
  int n = nbb >> 3, b = nbb & 7;
  int q0 = qt * 256;

  int tid = threadIdx.x;
  int w = tid >> 6, l = tid & 63;
  int m = l & 31, g = l >> 5;
  int qg = w & 7, dh = w >> 3;

  bf16x8 qf[16];
  {
    const unsigned short* qbase = Qb + (size_t)(b * 2048 + q0 + qg * 32 + m) * 1024 + n * 256 + g * 8;
#pragma unroll
    for (int ks = 0; ks < 16; ++ks)
      qf[ks] = *(const bf16x8*)(qbase + ks * 16);
  }

  f32x16 ao[4];
#pragma unroll
  for (int dt = 0; dt < 4; ++dt)
#pragma unroll
    for (int r = 0; r < 16; ++r) ao[dt][r] = 0.f;
  float m_s = -1e30f, l_s = 0.f;
  bf16x8 pa[4];

  // staging: wave stages K planes w*2..w*2+1 and V granule rows w*128..+128
  const unsigned short* kpl = Kg + (((size_t)(n * 8 + b) * 32 + w * 2) * 16384) + (size_t)l * 8;
  const unsigned short* vpl = Vt + ((size_t)(n * 8 + b) * 65536 + w * 128 + l) * 8;

#pragma unroll
  for (int jj = 0; jj < 2; ++jj) {
    gload16(kpl + jj * 16384, Ks[0] + ((w * 2 + jj) * 64) * 8);
    gload16(vpl + jj * 512,   Vs[0] + (w * 128 + jj * 64) * 8);
  }
  __syncthreads();

  for (int t = 0; t < 32; ++t) {
    int cur = t & 1;
    const unsigned short* Kc = Ks[cur];

    // K-prefetch(t+1): targets Ks[cur^1], last read at iter t-1 (safe).
    if (t < 31) {
      int tn = t + 1;
#pragma unroll
      for (int jj = 0; jj < 2; ++jj)
        gload16(kpl + jj * 16384 + tn * 512, Ks[cur ^ 1] + ((w * 2 + jj) * 64) * 8);
    }

    // QK^T swapped: s0/s1 = S[kv 0..31 / 32..63][q=lane&31]
    f32x16 s0, s1;
#pragma unroll
    for (int r = 0; r < 16; ++r) { s0[r] = 0.f; s1[r] = 0.f; }
    __builtin_amdgcn_s_setprio(1);
#pragma unroll
    for (int ks = 0; ks < 16; ++ks) {
      bf16x8 k0 = *(const bf16x8*)(Kc + ((2 * ks + g) * 64 + m) * 8);
      bf16x8 k1 = *(const bf16x8*)(Kc + ((2 * ks + g) * 64 + 32 + m) * 8);
      s0 = __builtin_amdgcn_mfma_f32_32x32x16_bf16(k0, qf[ks], s0, 0, 0, 0);
      s1 = __builtin_amdgcn_mfma_f32_32x32x16_bf16(k1, qf[ks], s1, 0, 0, 0);
    }

    // PV(t-1): reads Vs[cur^1] (V(t-1)); pa packed with m_(t-1); ao currently m_(t-1)-scaled.
    if (t > 0) {
      const unsigned short* Vp = Vs[cur ^ 1];
#pragma unroll
      for (int dt = 0; dt < 4; ++dt) {
        int vrow = dh * 128 + dt * 32 + m;
#pragma unroll
        for (int ks2 = 0; ks2 < 4; ++ks2) {
          bf16x8 vf = *(const bf16x8*)(Vp + ((2 * ks2 + g) * 256 + vrow) * 8);
          ao[dt] = __builtin_amdgcn_mfma_f32_32x32x16_bf16(pa[ks2], vf, ao[dt], 0, 0, 0);
        }
      }
    }
    __builtin_amdgcn_s_setprio(0);

    // mid barrier: all waves done reading Vs[cur^1]; drains K-prefetch (cheap).
    __syncthreads();

    // V-prefetch(t+1) into Vs[cur^1]
    if (t < 31) {
      int tn = t + 1;
#pragma unroll
      for (int jj = 0; jj < 2; ++jj)
        gload16(vpl + (size_t)tn * 16384 + jj * 512, Vs[cur ^ 1] + (w * 128 + jj * 64) * 8);
    }

    // ---- softmax(t) (exp2 domain; Q pre-scaled) ----
    float tm[16];
#pragma unroll
    for (int r = 0; r < 16; ++r) tm[r] = fmaxf(s0[r], s1[r]);
#pragma unroll
    for (int d = 8; d > 0; d >>= 1)
#pragma unroll
      for (int r = 0; r < d; ++r) tm[r] = fmaxf(tm[r], tm[r + d]);
    float vm = fmaxf(tm[0], __shfl_xor(tm[0], 32));

    if (__any(vm > m_s + 8.f)) {
      float mn = fmaxf(m_s, vm);
      float f = exp2f(m_s - mn);
      m_s = mn; l_s *= f;
#pragma unroll
      for (int r = 0; r < 16; ++r) {
        float fr = __shfl(f, 4 * g + (r & 3) + 8 * (r >> 2));
        ao[0][r] *= fr; ao[1][r] *= fr; ao[2][r] *= fr; ao[3][r] *= fr;
      }
    }

    float p0[16], p1[16];
#pragma unroll
    for (int r = 0; r < 16; ++r) {
      p0[r] = exp2f(s0[r] - m_s);
      p1[r] = exp2f(s1[r] - m_s);
    }
    float ts[16];
#pragma unroll
    for (int r = 0; r < 16; ++r) ts[r] = p0[r] + p1[r];
#pragma unroll
    for (int d = 8; d > 0; d >>= 1)
#pragma unroll
      for (int r = 0; r < d; ++r) ts[r] += ts[r + d];
    l_s += ts[0] + __shfl_xor(ts[0], 32);

    // pack P via v_cvt_pk_bf16_f32: pa[0]=p0[0..7], pa[1]=p0[8..15], pa[2]=p1[0..7], pa[3]=p1[8..15]
    {
      union { unsigned u[4]; bf16x8 v; } w0, w1, w2, w3;
#pragma unroll
      for (int wd = 0; wd < 4; ++wd) {
        w0.u[wd] = cvtpk(p0[2 * wd], p0[2 * wd + 1]);
        w1.u[wd] = cvtpk(p0[8 + 2 * wd], p0[8 + 2 * wd + 1]);
        w2.u[wd] = cvtpk(p1[2 * wd], p1[2 * wd + 1]);
        w3.u[wd] = cvtpk(p1[8 + 2 * wd], p1[8 + 2 * wd + 1]);
      }
      pa[0] = w0.v; pa[1] = w1.v; pa[2] = w2.v; pa[3] = w3.v;
    }

    // end barrier: drains V-prefetch; next iter reads Ks/Vs[cur^1].
    __syncthreads();
  }

  // final PV(31): V(31) lives in Vs[1]
  {
    const unsigned short* Vp = Vs[1];
    __builtin_amdgcn_s_setprio(1);
#pragma unroll
    for (int dt = 0; dt < 4; ++dt) {
      int vrow = dh * 128 + dt * 32 + m;
#pragma unroll
      for (int ks2 = 0; ks2 < 4; ++ks2) {
        bf16x8 vf = *(const bf16x8*)(Vp + ((2 * ks2 + g) * 256 + vrow) * 8);
        ao[dt] = __builtin_amdgcn_mfma_f32_32x32x16_bf16(pa[ks2], vf, ao[dt], 0, 0, 0);
      }
    }
    __builtin_amdgcn_s_setprio(0);
  }

  // epilogue
  float rinv[16];
#pragma unroll
  for (int r = 0; r < 16; ++r) {
    float lr = __shfl(l_s, 4 * g + (r & 3) + 8 * (r >> 2));
    rinv[r] = 1.f / lr;
  }
#pragma unroll
  for (int dt = 0; dt < 4; ++dt) {
    int col = n * 256 + dh * 128 + dt * 32 + m;
#pragma unroll
    for (int r = 0; r < 16; ++r) {
      int rowq = q0 + qg * 32 + 4 * g + (r & 3) + 8 * (r >> 2);
      comb[(size_t)(b * 2048 + rowq) * 1024 + col] = f2bf(ao[dt][r] * rinv[r]);
    }
  }
}

extern "C" void kernel_launch(void* const* d_in, const int* in_sizes, int n_in,
                              void* d_out, int out_size, void* d_ws, size_t ws_size,
                              hipStream_t stream) {
  const float* x  = (const float*)d_in[0];
  const float* Wq = (const float*)d_in[1];
  const float* bq = (const float*)d_in[2];
  const float* Wk = (const float*)d_in[3];
  const float* bk = (const float*)d_in[4];
  const float* Wv = (const float*)d_in[5];
  const float* bv = (const float*)d_in[6];
  const float* Wo = (const float*)d_in[7];
  const float* bo = (const float*)d_in[8];

  const size_t MB = 1ull << 20;
  char* ws = (char*)d_ws;
  unsigned short* xb  = (unsigned short*)(ws);            // 32MB (reused as comb)
  unsigned short* Wqt = (unsigned short*)(ws + 32 * MB);  // 2MB, contiguous B [3072][1024] starts here
  unsigned short* Wkt = (unsigned short*)(ws + 34 * MB);  // 2MB
  unsigned short* Wvt = (unsigned short*)(ws + 36 * MB);  // 2MB
  unsigned short* Wot = (unsigned short*)(ws + 38 * MB);  // 0.5MB
  unsigned short* Qb  = (unsigned short*)(ws + 40 * MB);  // 32MB
  unsigned short* Kg  = (unsigned short*)(ws + 72 * MB);  // 32MB (fragment-plane layout)
  unsigned short* Vt  = (unsigned short*)(ws + 104 * MB); // 32MB (granule layout, end: 136MB)
  unsigned short* comb = xb;

  k_cvt<<<2048, 256, 0, stream>>>(x, xb, 16384 * 1024 / 4);
  dim3 trb(32, 8);
  k_tr<<<dim3(8, 32, 4), trb, 0, stream>>>(Wq, Wqt, 1024, 256);
  k_tr<<<dim3(8, 32, 4), trb, 0, stream>>>(Wk, Wkt, 1024, 256);
  k_tr<<<dim3(8, 32, 4), trb, 0, stream>>>(Wv, Wvt, 1024, 256);
  k_tr<<<dim3(8, 32, 1), trb, 0, stream>>>(Wo, Wot, 1024, 256);

  const float qscale = 0.0625f * 1.44269504088896f;  // 1/sqrt(256) * log2(e)
  k_gemmqkv<<<dim3(12, 128), 512, 0, stream>>>(xb, Wqt, bq, bk, bv, Qb, Kg, Vt, qscale);

  k_attn<<<256, 1024, 0, stream>>>(Qb, Kg, Vt, comb);

  k_gemmo<<<dim3(1, 128), 512, 0, stream>>>(comb, Wot, bo, (float*)d_out);
}

// Round 9
// 556.460 us; speedup vs baseline: 1.0015x; 1.0013x over previous
//
#include <hip/hip_runtime.h>
#include <hip/hip_bf16.h>

typedef __attribute__((ext_vector_type(8))) short bf16x8;
typedef __attribute__((ext_vector_type(4))) float f32x4;
typedef __attribute__((ext_vector_type(16))) float f32x16;

#define DEVI __device__ __forceinline__

DEVI unsigned short f2bf(float f) {
  union { float f; unsigned u; } v; v.f = f;
  unsigned r = v.u + 0x7FFFu + ((v.u >> 16) & 1u);
  return (unsigned short)(r >> 16);
}

DEVI unsigned cvtpk(float lo, float hi) {
  unsigned r;
  asm("v_cvt_pk_bf16_f32 %0, %1, %2" : "=v"(r) : "v"(lo), "v"(hi));
  return r;
}

DEVI void gload16(const void* g, void* l) {
  __builtin_amdgcn_global_load_lds(
      (const __attribute__((address_space(1))) unsigned int*)g,
      (__attribute__((address_space(3))) unsigned int*)l, 16, 0, 0);
}

// ---------------- fp32 -> bf16 convert ----------------
__global__ void k_cvt(const float* __restrict__ in, unsigned short* __restrict__ out, int n4) {
  int i = blockIdx.x * blockDim.x + threadIdx.x;
  int stride = gridDim.x * blockDim.x;
  for (; i < n4; i += stride) {
    float4 v = ((const float4*)in)[i];
    ushort4 o;
    o.x = f2bf(v.x); o.y = f2bf(v.y); o.z = f2bf(v.z); o.w = f2bf(v.w);
    ((ushort4*)out)[i] = o;
  }
}

// ------------- transpose [R][C] f32 -> [C][R] bf16, batched over blockIdx.z -------------
__global__ void k_tr(const float* __restrict__ in, unsigned short* __restrict__ out, int R, int C) {
  __shared__ float t[32][33];
  size_t base = (size_t)blockIdx.z * R * C;
  int r0 = blockIdx.y * 32, c0 = blockIdx.x * 32;
  int tx = threadIdx.x, ty = threadIdx.y;
  for (int i = 0; i < 32; i += 8)
    t[ty + i][tx] = in[base + (size_t)(r0 + ty + i) * C + (c0 + tx)];
  __syncthreads();
  for (int i = 0; i < 32; i += 8)
    out[base + (size_t)(c0 + ty + i) * R + (r0 + tx)] = f2bf(t[tx][ty + i]);
}

// ---------------- fused QKV GEMM: [16384,1024] x [3072,1024]^T ----------------
__global__ __launch_bounds__(512, 4) void k_gemmqkv(
    const unsigned short* __restrict__ A,
    const unsigned short* __restrict__ B,
    const float* __restrict__ bq, const float* __restrict__ bk,
    const float* __restrict__ bv,
    unsigned short* __restrict__ Qb, unsigned short* __restrict__ Kg,
    unsigned short* __restrict__ Vt, float qscale)
{
  __shared__ unsigned short As[128 * 64];
  __shared__ unsigned short Bs[256 * 64];
  int tid = threadIdx.x;
  int w = tid >> 6, l = tid & 63;
  int lg = l >> 4, lm = l & 15;
  int wr = w >> 2, wc = w & 3;
  int row0 = blockIdx.y * 128, col0 = blockIdx.x * 256;

  const f32x4 fz = {0.f, 0.f, 0.f, 0.f};
  f32x4 acc[4][4];
  for (int i = 0; i < 4; i++) for (int j = 0; j < 4; j++) acc[i][j] = fz;

  for (int t = 0; t < 16; ++t) {
    int k0 = t << 6;
    __syncthreads();
#pragma unroll
    for (int j = 0; j < 2; ++j) {
      int ch = j * 512 + tid;
      int row = ch >> 3, cirp = (ch & 7) ^ (row & 7);
      gload16(A + (size_t)(row0 + row) * 1024 + k0 + cirp * 8,
              As + (size_t)(j * 512 + w * 64) * 8);
    }
#pragma unroll
    for (int j = 0; j < 4; ++j) {
      int ch = j * 512 + tid;
      int row = ch >> 3, cirp = (ch & 7) ^ (row & 7);
      gload16(B + (size_t)(col0 + row) * 1024 + k0 + cirp * 8,
              Bs + (size_t)(j * 512 + w * 64) * 8);
    }
    __syncthreads();
#pragma unroll
    for (int kt = 0; kt < 2; ++kt) {
      bf16x8 bfr[4];
#pragma unroll
      for (int ni = 0; ni < 4; ++ni) {
        int r = wc * 64 + ni * 16 + lm;
        bfr[ni] = *(const bf16x8*)((const char*)Bs + r * 128 + ((kt * 64 + lg * 16) ^ ((r & 7) << 4)));
      }
#pragma unroll
      for (int mi = 0; mi < 4; ++mi) {
        int r = wr * 64 + mi * 16 + lm;
        bf16x8 afr = *(const bf16x8*)((const char*)As + r * 128 + ((kt * 64 + lg * 16) ^ ((r & 7) << 4)));
#pragma unroll
        for (int ni = 0; ni < 4; ++ni)
          acc[mi][ni] = __builtin_amdgcn_mfma_f32_16x16x32_bf16(afr, bfr[ni], acc[mi][ni], 0, 0, 0);
      }
    }
  }

  int sel = col0 >> 10;                 // block-uniform: 0=Q, 1=K, 2=V
  const float* bb = sel == 0 ? bq : (sel == 1 ? bk : bv);
#pragma unroll
  for (int mi = 0; mi < 4; ++mi) {
#pragma unroll
    for (int ni = 0; ni < 4; ++ni) {
#pragma unroll
      for (int q = 0; q < 4; ++q) {
        int rg = row0 + wr * 64 + mi * 16 + lg * 4 + q;
        int cg = col0 + wc * 64 + ni * 16 + lm;
        int cl = cg & 1023;
        float val = acc[mi][ni][q] + bb[cl];
        int bI = rg >> 11, s = rg & 2047;
        int nn = cl >> 8, d = cl & 255;
        if (sel == 0) {
          Qb[(size_t)rg * 1024 + cl] = f2bf(val * qscale);
        } else if (sel == 1) {
          Kg[((size_t)((nn * 8 + bI) * 32 + (d >> 3))) * 16384 + (size_t)s * 8 + (d & 7)] = f2bf(val);
        } else {
          int t2 = s >> 6, u = s & 63;
          int p = ((u >> 4) & 3) * 2 + ((u >> 2) & 1);
          int jv = ((u >> 3) & 1) * 4 + (u & 3);
          Vt[(((size_t)(nn * 8 + bI) * 32 + t2) * 2048 + p * 256 + d) * 8 + jv] = f2bf(val);
        }
      }
    }
  }
}

// ---------------- output GEMM: [16384,1024] x [256,1024]^T -> fp32 + bo ----------------
__global__ __launch_bounds__(512, 4) void k_gemmo(
    const unsigned short* __restrict__ A,
    const unsigned short* __restrict__ B,
    const float* __restrict__ bias,
    float* __restrict__ Cout)
{
  __shared__ unsigned short As[128 * 64];
  __shared__ unsigned short Bs[256 * 64];
  int tid = threadIdx.x;
  int w = tid >> 6, l = tid & 63;
  int lg = l >> 4, lm = l & 15;
  int wr = w >> 2, wc = w & 3;
  int row0 = blockIdx.y * 128;

  const f32x4 fz = {0.f, 0.f, 0.f, 0.f};
  f32x4 acc[4][4];
  for (int i = 0; i < 4; i++) for (int j = 0; j < 4; j++) acc[i][j] = fz;

  for (int t = 0; t < 16; ++t) {
    int k0 = t << 6;
    __syncthreads();
#pragma unroll
    for (int j = 0; j < 2; ++j) {
      int ch = j * 512 + tid;
      int row = ch >> 3, cirp = (ch & 7) ^ (row & 7);
      gload16(A + (size_t)(row0 + row) * 1024 + k0 + cirp * 8,
              As + (size_t)(j * 512 + w * 64) * 8);
    }
#pragma unroll
    for (int j = 0; j < 4; ++j) {
      int ch = j * 512 + tid;
      int row = ch >> 3, cirp = (ch & 7) ^ (row & 7);
      gload16(B + (size_t)(row) * 1024 + k0 + cirp * 8,
              Bs + (size_t)(j * 512 + w * 64) * 8);
    }
    __syncthreads();
#pragma unroll
    for (int kt = 0; kt < 2; ++kt) {
      bf16x8 bfr[4];
#pragma unroll
      for (int ni = 0; ni < 4; ++ni) {
        int r = wc * 64 + ni * 16 + lm;
        bfr[ni] = *(const bf16x8*)((const char*)Bs + r * 128 + ((kt * 64 + lg * 16) ^ ((r & 7) << 4)));
      }
#pragma unroll
      for (int mi = 0; mi < 4; ++mi) {
        int r = wr * 64 + mi * 16 + lm;
        bf16x8 afr = *(const bf16x8*)((const char*)As + r * 128 + ((kt * 64 + lg * 16) ^ ((r & 7) << 4)));
#pragma unroll
        for (int ni = 0; ni < 4; ++ni)
          acc[mi][ni] = __builtin_amdgcn_mfma_f32_16x16x32_bf16(afr, bfr[ni], acc[mi][ni], 0, 0, 0);
      }
    }
  }

#pragma unroll
  for (int mi = 0; mi < 4; ++mi)
#pragma unroll
    for (int ni = 0; ni < 4; ++ni)
#pragma unroll
      for (int q = 0; q < 4; ++q) {
        int rg = row0 + wr * 64 + mi * 16 + lg * 4 + q;
        int cg = wc * 64 + ni * 16 + lm;
        Cout[(size_t)rg * 256 + cg] = acc[mi][ni][q] + bias[cg];
      }
}

// ---------------- flash attention (pipelined, 16 waves / 256 q rows) ----------------
// block = 256 q rows of one (n,b); 16 waves: qg=w&7 (32 q rows), dh=w>>3 (d half).
// iter t: [K-prefetch(t+1)] [QK(t)] [PV(t-1)] [sync] [V-prefetch(t+1)] [softmax(t)->pa(t)] [sync]
// NOTE: hipcc's 2nd launch_bounds arg behaves as min BLOCKS/CU (measured r7/r8:
// (1024,2)->64 VGPR cap). (1024,1) -> 16 waves/CU -> 128 VGPR cap, no spill.
__global__ __launch_bounds__(1024, 1) void k_attn(
    const unsigned short* __restrict__ Qb,
    const unsigned short* __restrict__ Kg,
    const unsigned short* __restrict__ Vt,
    unsigned short* __restrict__ comb)
{
  __shared__ unsigned short Ks[2][2048 * 8];
  __shared__ unsigned short Vs[2][2048 * 8];

  int i = blockIdx.x;
  int c = i & 7, j = i >> 3;
  int nbb = c + 8 * (j >> 3);
  int qt = j & 7;
  int n = nbb >> 3, b = nbb & 7;
  int q0 = qt * 256;

  int tid = threadIdx.x;
  int w = tid >> 6, l = tid & 63;
  int m = l & 31, g = l >> 5;
  int qg = w & 7, dh = w >> 3;

  bf16x8 qf[16];
  {
    const unsigned short* qbase = Qb + (size_t)(b * 2048 + q0 + qg * 32 + m) * 1024 + n * 256 + g * 8;
#pragma unroll
    for (int ks = 0; ks < 16; ++ks)
      qf[ks] = *(const bf16x8*)(qbase + ks * 16);
  }

  f32x16 ao[4];
#pragma unroll
  for (int dt = 0; dt < 4; ++dt)
#pragma unroll
    for (int r = 0; r < 16; ++r) ao[dt][r] = 0.f;
  float m_s = -1e30f, l_s = 0.f;
  bf16x8 pa[4];

  // staging: wave stages K planes w*2..w*2+1 and V granule rows w*128..+128
  const unsigned short* kpl = Kg + (((size_t)(n * 8 + b) * 32 + w * 2) * 16384) + (size_t)l * 8;
  const unsigned short* vpl = Vt + ((size_t)(n * 8 + b) * 65536 + w * 128 + l) * 8;

#pragma unroll
  for (int jj = 0; jj < 2; ++jj) {
    gload16(kpl + jj * 16384, Ks[0] + ((w * 2 + jj) * 64) * 8);
    gload16(vpl + jj * 512,   Vs[0] + (w * 128 + jj * 64) * 8);
  }
  __syncthreads();

  for (int t = 0; t < 32; ++t) {
    int cur = t & 1;
    const unsigned short* Kc = Ks[cur];

    // K-prefetch(t+1): targets Ks[cur^1], last read at iter t-1 (safe).
    if (t < 31) {
      int tn = t + 1;
#pragma unroll
      for (int jj = 0; jj < 2; ++jj)
        gload16(kpl + jj * 16384 + tn * 512, Ks[cur ^ 1] + ((w * 2 + jj) * 64) * 8);
    }

    // QK^T swapped: s0/s1 = S[kv 0..31 / 32..63][q=lane&31]
    f32x16 s0, s1;
#pragma unroll
    for (int r = 0; r < 16; ++r) { s0[r] = 0.f; s1[r] = 0.f; }
    __builtin_amdgcn_s_setprio(1);
#pragma unroll
    for (int ks = 0; ks < 16; ++ks) {
      bf16x8 k0 = *(const bf16x8*)(Kc + ((2 * ks + g) * 64 + m) * 8);
      bf16x8 k1 = *(const bf16x8*)(Kc + ((2 * ks + g) * 64 + 32 + m) * 8);
      s0 = __builtin_amdgcn_mfma_f32_32x32x16_bf16(k0, qf[ks], s0, 0, 0, 0);
      s1 = __builtin_amdgcn_mfma_f32_32x32x16_bf16(k1, qf[ks], s1, 0, 0, 0);
    }

    // PV(t-1): reads Vs[cur^1] (V(t-1)); pa packed with m_(t-1); ao currently m_(t-1)-scaled.
    if (t > 0) {
      const unsigned short* Vp = Vs[cur ^ 1];
#pragma unroll
      for (int dt = 0; dt < 4; ++dt) {
        int vrow = dh * 128 + dt * 32 + m;
#pragma unroll
        for (int ks2 = 0; ks2 < 4; ++ks2) {
          bf16x8 vf = *(const bf16x8*)(Vp + ((2 * ks2 + g) * 256 + vrow) * 8);
          ao[dt] = __builtin_amdgcn_mfma_f32_32x32x16_bf16(pa[ks2], vf, ao[dt], 0, 0, 0);
        }
      }
    }
    __builtin_amdgcn_s_setprio(0);

    // mid barrier: all waves done reading Vs[cur^1]; drains K-prefetch (cheap).
    __syncthreads();

    // V-prefetch(t+1) into Vs[cur^1]
    if (t < 31) {
      int tn = t + 1;
#pragma unroll
      for (int jj = 0; jj < 2; ++jj)
        gload16(vpl + (size_t)tn * 16384 + jj * 512, Vs[cur ^ 1] + (w * 128 + jj * 64) * 8);
    }

    // ---- softmax(t) (exp2 domain; Q pre-scaled) ----
    float tm[16];
#pragma unroll
    for (int r = 0; r < 16; ++r) tm[r] = fmaxf(s0[r], s1[r]);
#pragma unroll
    for (int d = 8; d > 0; d >>= 1)
#pragma unroll
      for (int r = 0; r < d; ++r) tm[r] = fmaxf(tm[r], tm[r + d]);
    float vm = fmaxf(tm[0], __shfl_xor(tm[0], 32));

    if (__any(vm > m_s + 8.f)) {
      float mn = fmaxf(m_s, vm);
      float f = exp2f(m_s - mn);
      m_s = mn; l_s *= f;
#pragma unroll
      for (int r = 0; r < 16; ++r) {
        float fr = __shfl(f, 4 * g + (r & 3) + 8 * (r >> 2));
        ao[0][r] *= fr; ao[1][r] *= fr; ao[2][r] *= fr; ao[3][r] *= fr;
      }
    }

    float p0[16], p1[16];
#pragma unroll
    for (int r = 0; r < 16; ++r) {
      p0[r] = exp2f(s0[r] - m_s);
      p1[r] = exp2f(s1[r] - m_s);
    }
    float ts[16];
#pragma unroll
    for (int r = 0; r < 16; ++r) ts[r] = p0[r] + p1[r];
#pragma unroll
    for (int d = 8; d > 0; d >>= 1)
#pragma unroll
      for (int r = 0; r < d; ++r) ts[r] += ts[r + d];
    l_s += ts[0] + __shfl_xor(ts[0], 32);

    // pack P via v_cvt_pk_bf16_f32: pa[0]=p0[0..7], pa[1]=p0[8..15], pa[2]=p1[0..7], pa[3]=p1[8..15]
    {
      union { unsigned u[4]; bf16x8 v; } w0, w1, w2, w3;
#pragma unroll
      for (int wd = 0; wd < 4; ++wd) {
        w0.u[wd] = cvtpk(p0[2 * wd], p0[2 * wd + 1]);
        w1.u[wd] = cvtpk(p0[8 + 2 * wd], p0[8 + 2 * wd + 1]);
        w2.u[wd] = cvtpk(p1[2 * wd], p1[2 * wd + 1]);
        w3.u[wd] = cvtpk(p1[8 + 2 * wd], p1[8 + 2 * wd + 1]);
      }
      pa[0] = w0.v; pa[1] = w1.v; pa[2] = w2.v; pa[3] = w3.v;
    }

    // end barrier: drains V-prefetch; next iter reads Ks/Vs[cur^1].
    __syncthreads();
  }

  // final PV(31): V(31) lives in Vs[1]
  {
    const unsigned short* Vp = Vs[1];
    __builtin_amdgcn_s_setprio(1);
#pragma unroll
    for (int dt = 0; dt < 4; ++dt) {
      int vrow = dh * 128 + dt * 32 + m;
#pragma unroll
      for (int ks2 = 0; ks2 < 4; ++ks2) {
        bf16x8 vf = *(const bf16x8*)(Vp + ((2 * ks2 + g) * 256 + vrow) * 8);
        ao[dt] = __builtin_amdgcn_mfma_f32_32x32x16_bf16(pa[ks2], vf, ao[dt], 0, 0, 0);
      }
    }
    __builtin_amdgcn_s_setprio(0);
  }

  // epilogue
  float rinv[16];
#pragma unroll
  for (int r = 0; r < 16; ++r) {
    float lr = __shfl(l_s, 4 * g + (r & 3) + 8 * (r >> 2));
    rinv[r] = 1.f / lr;
  }
#pragma unroll
  for (int dt = 0; dt < 4; ++dt) {
    int col = n * 256 + dh * 128 + dt * 32 + m;
#pragma unroll
    for (int r = 0; r < 16; ++r) {
      int rowq = q0 + qg * 32 + 4 * g + (r & 3) + 8 * (r >> 2);
      comb[(size_t)(b * 2048 + rowq) * 1024 + col] = f2bf(ao[dt][r] * rinv[r]);
    }
  }
}

extern "C" void kernel_launch(void* const* d_in, const int* in_sizes, int n_in,
                              void* d_out, int out_size, void* d_ws, size_t ws_size,
                              hipStream_t stream) {
  const float* x  = (const float*)d_in[0];
  const float* Wq = (const float*)d_in[1];
  const float* bq = (const float*)d_in[2];
  const float* Wk = (const float*)d_in[3];
  const float* bk = (const float*)d_in[4];
  const float* Wv = (const float*)d_in[5];
  const float* bv = (const float*)d_in[6];
  const float* Wo = (const float*)d_in[7];
  const float* bo = (const float*)d_in[8];

  const size_t MB = 1ull << 20;
  char* ws = (char*)d_ws;
  unsigned short* xb  = (unsigned short*)(ws);            // 32MB (reused as comb)
  unsigned short* Wqt = (unsigned short*)(ws + 32 * MB);  // 2MB, contiguous B [3072][1024] starts here
  unsigned short* Wkt = (unsigned short*)(ws + 34 * MB);  // 2MB
  unsigned short* Wvt = (unsigned short*)(ws + 36 * MB);  // 2MB
  unsigned short* Wot = (unsigned short*)(ws + 38 * MB);  // 0.5MB
  unsigned short* Qb  = (unsigned short*)(ws + 40 * MB);  // 32MB
  unsigned short* Kg  = (unsigned short*)(ws + 72 * MB);  // 32MB (fragment-plane layout)
  unsigned short* Vt  = (unsigned short*)(ws + 104 * MB); // 32MB (granule layout, end: 136MB)
  unsigned short* comb = xb;

  k_cvt<<<2048, 256, 0, stream>>>(x, xb, 16384 * 1024 / 4);
  dim3 trb(32, 8);
  k_tr<<<dim3(8, 32, 4), trb, 0, stream>>>(Wq, Wqt, 1024, 256);
  k_tr<<<dim3(8, 32, 4), trb, 0, stream>>>(Wk, Wkt, 1024, 256);
  k_tr<<<dim3(8, 32, 4), trb, 0, stream>>>(Wv, Wvt, 1024, 256);
  k_tr<<<dim3(8, 32, 1), trb, 0, stream>>>(Wo, Wot, 1024, 256);

  const float qscale = 0.0625f * 1.44269504088896f;  // 1/sqrt(256) * log2(e)
  k_gemmqkv<<<dim3(12, 128), 512, 0, stream>>>(xb, Wqt, bq, bk, bv, Qb, Kg, Vt, qscale);

  k_attn<<<256, 1024, 0, stream>>>(Qb, Kg, Vt, comb);

  k_gemmo<<<dim3(1, 128), 512, 0, stream>>>(comb, Wot, bo, (float*)d_out);
}

// Round 10
// 393.824 us; speedup vs baseline: 1.4151x; 1.4130x over previous
//
#include <hip/hip_runtime.h>
#include <hip/hip_bf16.h>

typedef __attribute__((ext_vector_type(8))) short bf16x8;
typedef __attribute__((ext_vector_type(4))) float f32x4;
typedef __attribute__((ext_vector_type(16))) float f32x16;

#define DEVI __device__ __forceinline__

DEVI unsigned short f2bf(float f) {
  union { float f; unsigned u; } v; v.f = f;
  unsigned r = v.u + 0x7FFFu + ((v.u >> 16) & 1u);
  return (unsigned short)(r >> 16);
}

DEVI unsigned cvtpk(float lo, float hi) {
  unsigned r;
  asm("v_cvt_pk_bf16_f32 %0, %1, %2" : "=v"(r) : "v"(lo), "v"(hi));
  return r;
}

DEVI void gload16(const void* g, void* l) {
  __builtin_amdgcn_global_load_lds(
      (const __attribute__((address_space(1))) unsigned int*)g,
      (__attribute__((address_space(3))) unsigned int*)l, 16, 0, 0);
}

// ---------------- fp32 -> bf16 convert ----------------
__global__ void k_cvt(const float* __restrict__ in, unsigned short* __restrict__ out, int n4) {
  int i = blockIdx.x * blockDim.x + threadIdx.x;
  int stride = gridDim.x * blockDim.x;
  for (; i < n4; i += stride) {
    float4 v = ((const float4*)in)[i];
    ushort4 o;
    o.x = f2bf(v.x); o.y = f2bf(v.y); o.z = f2bf(v.z); o.w = f2bf(v.w);
    ((ushort4*)out)[i] = o;
  }
}

// ------------- transpose [R][C] f32 -> [C][R] bf16, batched over blockIdx.z -------------
__global__ void k_tr(const float* __restrict__ in, unsigned short* __restrict__ out, int R, int C) {
  __shared__ float t[32][33];
  size_t base = (size_t)blockIdx.z * R * C;
  int r0 = blockIdx.y * 32, c0 = blockIdx.x * 32;
  int tx = threadIdx.x, ty = threadIdx.y;
  for (int i = 0; i < 32; i += 8)
    t[ty + i][tx] = in[base + (size_t)(r0 + ty + i) * C + (c0 + tx)];
  __syncthreads();
  for (int i = 0; i < 32; i += 8)
    out[base + (size_t)(c0 + ty + i) * R + (r0 + tx)] = f2bf(t[tx][ty + i]);
}

// ---------------- fused QKV GEMM: [16384,1024] x [3072,1024]^T ----------------
__global__ __launch_bounds__(512, 4) void k_gemmqkv(
    const unsigned short* __restrict__ A,
    const unsigned short* __restrict__ B,
    const float* __restrict__ bq, const float* __restrict__ bk,
    const float* __restrict__ bv,
    unsigned short* __restrict__ Qb, unsigned short* __restrict__ Kg,
    unsigned short* __restrict__ Vt, float qscale)
{
  __shared__ unsigned short As[128 * 64];
  __shared__ unsigned short Bs[256 * 64];
  int tid = threadIdx.x;
  int w = tid >> 6, l = tid & 63;
  int lg = l >> 4, lm = l & 15;
  int wr = w >> 2, wc = w & 3;
  int row0 = blockIdx.y * 128, col0 = blockIdx.x * 256;

  const f32x4 fz = {0.f, 0.f, 0.f, 0.f};
  f32x4 acc[4][4];
  for (int i = 0; i < 4; i++) for (int j = 0; j < 4; j++) acc[i][j] = fz;

  for (int t = 0; t < 16; ++t) {
    int k0 = t << 6;
    __syncthreads();
#pragma unroll
    for (int j = 0; j < 2; ++j) {
      int ch = j * 512 + tid;
      int row = ch >> 3, cirp = (ch & 7) ^ (row & 7);
      gload16(A + (size_t)(row0 + row) * 1024 + k0 + cirp * 8,
              As + (size_t)(j * 512 + w * 64) * 8);
    }
#pragma unroll
    for (int j = 0; j < 4; ++j) {
      int ch = j * 512 + tid;
      int row = ch >> 3, cirp = (ch & 7) ^ (row & 7);
      gload16(B + (size_t)(col0 + row) * 1024 + k0 + cirp * 8,
              Bs + (size_t)(j * 512 + w * 64) * 8);
    }
    __syncthreads();
#pragma unroll
    for (int kt = 0; kt < 2; ++kt) {
      bf16x8 bfr[4];
#pragma unroll
      for (int ni = 0; ni < 4; ++ni) {
        int r = wc * 64 + ni * 16 + lm;
        bfr[ni] = *(const bf16x8*)((const char*)Bs + r * 128 + ((kt * 64 + lg * 16) ^ ((r & 7) << 4)));
      }
#pragma unroll
      for (int mi = 0; mi < 4; ++mi) {
        int r = wr * 64 + mi * 16 + lm;
        bf16x8 afr = *(const bf16x8*)((const char*)As + r * 128 + ((kt * 64 + lg * 16) ^ ((r & 7) << 4)));
#pragma unroll
        for (int ni = 0; ni < 4; ++ni)
          acc[mi][ni] = __builtin_amdgcn_mfma_f32_16x16x32_bf16(afr, bfr[ni], acc[mi][ni], 0, 0, 0);
      }
    }
  }

  int sel = col0 >> 10;                 // block-uniform: 0=Q, 1=K, 2=V
  const float* bb = sel == 0 ? bq : (sel == 1 ? bk : bv);
#pragma unroll
  for (int mi = 0; mi < 4; ++mi) {
#pragma unroll
    for (int ni = 0; ni < 4; ++ni) {
#pragma unroll
      for (int q = 0; q < 4; ++q) {
        int rg = row0 + wr * 64 + mi * 16 + lg * 4 + q;
        int cg = col0 + wc * 64 + ni * 16 + lm;
        int cl = cg & 1023;
        float val = acc[mi][ni][q] + bb[cl];
        int bI = rg >> 11, s = rg & 2047;
        int nn = cl >> 8, d = cl & 255;
        if (sel == 0) {
          Qb[(size_t)rg * 1024 + cl] = f2bf(val * qscale);
        } else if (sel == 1) {
          Kg[((size_t)((nn * 8 + bI) * 32 + (d >> 3))) * 16384 + (size_t)s * 8 + (d & 7)] = f2bf(val);
        } else {
          int t2 = s >> 6, u = s & 63;
          int p = ((u >> 4) & 3) * 2 + ((u >> 2) & 1);
          int jv = ((u >> 3) & 1) * 4 + (u & 3);
          Vt[(((size_t)(nn * 8 + bI) * 32 + t2) * 2048 + p * 256 + d) * 8 + jv] = f2bf(val);
        }
      }
    }
  }
}

// ---------------- output GEMM: [16384,1024] x [256,1024]^T -> fp32 + bo ----------------
__global__ __launch_bounds__(512, 4) void k_gemmo(
    const unsigned short* __restrict__ A,
    const unsigned short* __restrict__ B,
    const float* __restrict__ bias,
    float* __restrict__ Cout)
{
  __shared__ unsigned short As[128 * 64];
  __shared__ unsigned short Bs[256 * 64];
  int tid = threadIdx.x;
  int w = tid >> 6, l = tid & 63;
  int lg = l >> 4, lm = l & 15;
  int wr = w >> 2, wc = w & 3;
  int row0 = blockIdx.y * 128;

  const f32x4 fz = {0.f, 0.f, 0.f, 0.f};
  f32x4 acc[4][4];
  for (int i = 0; i < 4; i++) for (int j = 0; j < 4; j++) acc[i][j] = fz;

  for (int t = 0; t < 16; ++t) {
    int k0 = t << 6;
    __syncthreads();
#pragma unroll
    for (int j = 0; j < 2; ++j) {
      int ch = j * 512 + tid;
      int row = ch >> 3, cirp = (ch & 7) ^ (row & 7);
      gload16(A + (size_t)(row0 + row) * 1024 + k0 + cirp * 8,
              As + (size_t)(j * 512 + w * 64) * 8);
    }
#pragma unroll
    for (int j = 0; j < 4; ++j) {
      int ch = j * 512 + tid;
      int row = ch >> 3, cirp = (ch & 7) ^ (row & 7);
      gload16(B + (size_t)(row) * 1024 + k0 + cirp * 8,
              Bs + (size_t)(j * 512 + w * 64) * 8);
    }
    __syncthreads();
#pragma unroll
    for (int kt = 0; kt < 2; ++kt) {
      bf16x8 bfr[4];
#pragma unroll
      for (int ni = 0; ni < 4; ++ni) {
        int r = wc * 64 + ni * 16 + lm;
        bfr[ni] = *(const bf16x8*)((const char*)Bs + r * 128 + ((kt * 64 + lg * 16) ^ ((r & 7) << 4)));
      }
#pragma unroll
      for (int mi = 0; mi < 4; ++mi) {
        int r = wr * 64 + mi * 16 + lm;
        bf16x8 afr = *(const bf16x8*)((const char*)As + r * 128 + ((kt * 64 + lg * 16) ^ ((r & 7) << 4)));
#pragma unroll
        for (int ni = 0; ni < 4; ++ni)
          acc[mi][ni] = __builtin_amdgcn_mfma_f32_16x16x32_bf16(afr, bfr[ni], acc[mi][ni], 0, 0, 0);
      }
    }
  }

#pragma unroll
  for (int mi = 0; mi < 4; ++mi)
#pragma unroll
    for (int ni = 0; ni < 4; ++ni)
#pragma unroll
      for (int q = 0; q < 4; ++q) {
        int rg = row0 + wr * 64 + mi * 16 + lg * 4 + q;
        int cg = wc * 64 + ni * 16 + lm;
        Cout[(size_t)rg * 256 + cg] = acc[mi][ni][q] + bias[cg];
      }
}

// ---------------- flash attention (T15 pipelined, 8 waves / 128 q rows) ----------------
// iter t: [pref K(t+1),V(t+1)] [QK(t) MFMA || softmax(t-1) VALU] [PV(t-1)] [barrier]
// K double-buffered (2x32KB), V triple-buffered (3x32KB) -> 160KB LDS, ONE barrier/iter.

#define SOFTMAX_PV(P0, P1)                                                     \
  {                                                                            \
    float tm[16];                                                              \
    _Pragma("unroll") for (int r = 0; r < 16; ++r) tm[r] = fmaxf(P0[r], P1[r]);\
    _Pragma("unroll") for (int d = 8; d > 0; d >>= 1)                          \
      _Pragma("unroll") for (int r = 0; r < d; ++r) tm[r] = fmaxf(tm[r], tm[r + d]); \
    float vm = fmaxf(tm[0], __shfl_xor(tm[0], 32));                            \
    if (__any(vm > m_s + 8.f)) {                                               \
      float mn = fmaxf(m_s, vm);                                               \
      float f = exp2f(m_s - mn);                                               \
      m_s = mn; l_s *= f;                                                      \
      _Pragma("unroll") for (int r = 0; r < 16; ++r) {                         \
        float fr = __shfl(f, 4 * g + (r & 3) + 8 * (r >> 2));                  \
        ao[0][r] *= fr; ao[1][r] *= fr; ao[2][r] *= fr; ao[3][r] *= fr;        \
      }                                                                        \
    }                                                                          \
    _Pragma("unroll") for (int r = 0; r < 16; ++r) {                           \
      P0[r] = exp2f(P0[r] - m_s);                                              \
      P1[r] = exp2f(P1[r] - m_s);                                              \
    }                                                                          \
    float ts[16];                                                              \
    _Pragma("unroll") for (int r = 0; r < 16; ++r) ts[r] = P0[r] + P1[r];      \
    _Pragma("unroll") for (int d = 8; d > 0; d >>= 1)                          \
      _Pragma("unroll") for (int r = 0; r < d; ++r) ts[r] += ts[r + d];        \
    l_s += ts[0] + __shfl_xor(ts[0], 32);                                      \
    {                                                                          \
      union { unsigned u[4]; bf16x8 v; } w0_, w1_, w2_, w3_;                   \
      _Pragma("unroll") for (int wd = 0; wd < 4; ++wd) {                       \
        w0_.u[wd] = cvtpk(P0[2 * wd], P0[2 * wd + 1]);                         \
        w1_.u[wd] = cvtpk(P0[8 + 2 * wd], P0[8 + 2 * wd + 1]);                 \
        w2_.u[wd] = cvtpk(P1[2 * wd], P1[2 * wd + 1]);                         \
        w3_.u[wd] = cvtpk(P1[8 + 2 * wd], P1[8 + 2 * wd + 1]);                 \
      }                                                                        \
      pa[0] = w0_.v; pa[1] = w1_.v; pa[2] = w2_.v; pa[3] = w3_.v;              \
    }                                                                          \
    const unsigned short* Vp = &VsL[vr * 16384];                               \
    _Pragma("unroll") for (int dt = 0; dt < 4; ++dt) {                         \
      int vrow = dh * 128 + dt * 32 + m;                                       \
      _Pragma("unroll") for (int ks2 = 0; ks2 < 4; ++ks2) {                    \
        bf16x8 vf = *(const bf16x8*)(Vp + ((2 * ks2 + g) * 256 + vrow) * 8);   \
        ao[dt] = __builtin_amdgcn_mfma_f32_32x32x16_bf16(pa[ks2], vf, ao[dt], 0, 0, 0); \
      }                                                                        \
    }                                                                          \
  }

#define AITER(T, C0, C1, P0, P1, DOPREV, DOPREF)                               \
  do {                                                                         \
    const unsigned short* Kc = &KsL[((T) & 1) * 16384];                        \
    if (DOPREF) {                                                              \
      int tn = (T) + 1;                                                        \
      unsigned short* kd = &KsL[(tn & 1) * 16384];                             \
      unsigned short* vd = &VsL[vw * 16384];                                   \
      _Pragma("unroll") for (int jj = 0; jj < 4; ++jj) {                       \
        gload16(kpl + jj * 16384 + tn * 512, kd + ((w * 4 + jj) * 64) * 8);    \
        gload16(vpl + (size_t)tn * 16384 + jj * 512, vd + (w * 256 + jj * 64) * 8); \
      }                                                                        \
    }                                                                          \
    _Pragma("unroll") for (int r = 0; r < 16; ++r) { C0[r] = 0.f; C1[r] = 0.f; } \
    _Pragma("unroll") for (int ks = 0; ks < 16; ++ks) {                        \
      bf16x8 k0 = *(const bf16x8*)(Kc + ((2 * ks + g) * 64 + m) * 8);          \
      bf16x8 k1 = *(const bf16x8*)(Kc + ((2 * ks + g) * 64 + 32 + m) * 8);     \
      C0 = __builtin_amdgcn_mfma_f32_32x32x16_bf16(k0, qf[ks], C0, 0, 0, 0);   \
      C1 = __builtin_amdgcn_mfma_f32_32x32x16_bf16(k1, qf[ks], C1, 0, 0, 0);   \
    }                                                                          \
    if (DOPREV) SOFTMAX_PV(P0, P1);                                            \
    __syncthreads();                                                           \
    vr = vr == 2 ? 0 : vr + 1;                                                 \
    vw = vw == 2 ? 0 : vw + 1;                                                 \
  } while (0)

__global__ __launch_bounds__(512) void k_attn(
    const unsigned short* __restrict__ Qb,
    const unsigned short* __restrict__ Kg,
    const unsigned short* __restrict__ Vt,
    unsigned short* __restrict__ comb)
{
  __shared__ unsigned short KsL[2 * 16384];   // 64KB: K double-buffer
  __shared__ unsigned short VsL[3 * 16384];   // 96KB: V triple-buffer

  int i = blockIdx.x;
  int c = i & 7, j = i >> 3;
  int nbb = c + 8 * (j >> 4);
  int qt = j & 15;
  int n = nbb >> 3, b = nbb & 7;
  int q0 = qt * 128;

  int tid = threadIdx.x;
  int w = tid >> 6, l = tid & 63;
  int m = l & 31, g = l >> 5;
  int qg = w & 3, dh = w >> 2;

  bf16x8 qf[16];
  {
    const unsigned short* qbase = Qb + (size_t)(b * 2048 + q0 + qg * 32 + m) * 1024 + n * 256 + g * 8;
#pragma unroll
    for (int ks = 0; ks < 16; ++ks)
      qf[ks] = *(const bf16x8*)(qbase + ks * 16);
  }

  f32x16 ao[4];
#pragma unroll
  for (int dt = 0; dt < 4; ++dt)
#pragma unroll
    for (int r = 0; r < 16; ++r) ao[dt][r] = 0.f;
  float m_s = -1e30f, l_s = 0.f;
  bf16x8 pa[4];
  f32x16 sE0, sE1, sO0, sO1;

  const unsigned short* kpl = Kg + (((size_t)(n * 8 + b) * 32 + w * 4) * 16384) + (size_t)l * 8;
  const unsigned short* vpl = Vt + ((size_t)(n * 8 + b) * 65536 + w * 256 + l) * 8;

  int vr = 2, vw = 1;

  // prologue: K(0)->Ks[0], V(0)->Vs[0]
#pragma unroll
  for (int jj = 0; jj < 4; ++jj) {
    gload16(kpl + jj * 16384, KsL + ((w * 4 + jj) * 64) * 8);
    gload16(vpl + jj * 512,   VsL + (w * 256 + jj * 64) * 8);
  }
  __syncthreads();

  AITER(0, sE0, sE1, sO0, sO1, false, true);
  for (int tt = 0; tt < 15; ++tt) {
    int t1 = 2 * tt + 1, t2 = 2 * tt + 2;
    AITER(t1, sO0, sO1, sE0, sE1, true, true);
    AITER(t2, sE0, sE1, sO0, sO1, true, true);
  }
  AITER(31, sO0, sO1, sE0, sE1, true, false);
  SOFTMAX_PV(sO0, sO1);   // SM(31) + PV(31), reads Vs[vr==1]

  // epilogue
  float rinv[16];
#pragma unroll
  for (int r = 0; r < 16; ++r) {
    float lr = __shfl(l_s, 4 * g + (r & 3) + 8 * (r >> 2));
    rinv[r] = 1.f / lr;
  }
#pragma unroll
  for (int dt = 0; dt < 4; ++dt) {
    int col = n * 256 + dh * 128 + dt * 32 + m;
#pragma unroll
    for (int r = 0; r < 16; ++r) {
      int rowq = q0 + qg * 32 + 4 * g + (r & 3) + 8 * (r >> 2);
      comb[(size_t)(b * 2048 + rowq) * 1024 + col] = f2bf(ao[dt][r] * rinv[r]);
    }
  }
}

extern "C" void kernel_launch(void* const* d_in, const int* in_sizes, int n_in,
                              void* d_out, int out_size, void* d_ws, size_t ws_size,
                              hipStream_t stream) {
  const float* x  = (const float*)d_in[0];
  const float* Wq = (const float*)d_in[1];
  const float* bq = (const float*)d_in[2];
  const float* Wk = (const float*)d_in[3];
  const float* bk = (const float*)d_in[4];
  const float* Wv = (const float*)d_in[5];
  const float* bv = (const float*)d_in[6];
  const float* Wo = (const float*)d_in[7];
  const float* bo = (const float*)d_in[8];

  const size_t MB = 1ull << 20;
  char* ws = (char*)d_ws;
  unsigned short* xb  = (unsigned short*)(ws);            // 32MB (reused as comb)
  unsigned short* Wqt = (unsigned short*)(ws + 32 * MB);  // 2MB, contiguous B [3072][1024] starts here
  unsigned short* Wkt = (unsigned short*)(ws + 34 * MB);  // 2MB
  unsigned short* Wvt = (unsigned short*)(ws + 36 * MB);  // 2MB
  unsigned short* Wot = (unsigned short*)(ws + 38 * MB);  // 0.5MB
  unsigned short* Qb  = (unsigned short*)(ws + 40 * MB);  // 32MB
  unsigned short* Kg  = (unsigned short*)(ws + 72 * MB);  // 32MB (fragment-plane layout)
  unsigned short* Vt  = (unsigned short*)(ws + 104 * MB); // 32MB (granule layout, end: 136MB)
  unsigned short* comb = xb;

  k_cvt<<<2048, 256, 0, stream>>>(x, xb, 16384 * 1024 / 4);
  dim3 trb(32, 8);
  k_tr<<<dim3(8, 32, 4), trb, 0, stream>>>(Wq, Wqt, 1024, 256);
  k_tr<<<dim3(8, 32, 4), trb, 0, stream>>>(Wk, Wkt, 1024, 256);
  k_tr<<<dim3(8, 32, 4), trb, 0, stream>>>(Wv, Wvt, 1024, 256);
  k_tr<<<dim3(8, 32, 1), trb, 0, stream>>>(Wo, Wot, 1024, 256);

  const float qscale = 0.0625f * 1.44269504088896f;  // 1/sqrt(256) * log2(e)
  k_gemmqkv<<<dim3(12, 128), 512, 0, stream>>>(xb, Wqt, bq, bk, bv, Qb, Kg, Vt, qscale);

  k_attn<<<512, 512, 0, stream>>>(Qb, Kg, Vt, comb);

  k_gemmo<<<dim3(1, 128), 512, 0, stream>>>(comb, Wot, bo, (float*)d_out);
}